// Round 16
// baseline (735.423 us; speedup 1.0000x reference)
//
#include <hip/hip_runtime.h>
#include <cfloat>
#include <cmath>

#define SEP_ID 102
#define Bsz 64
#define Lseq 512
#define Hd 1024

typedef unsigned long long u64;

// ---- workspace layout (float offsets) ----
// TOTAL = 1,445,888 floats = 5.78 MB — proven-safe footprint (R3/R6/R8-R15).
#define OFF_HBUF     0u          // u64[64][2][1024] = 262144 floats (8B aligned @0)
#define OFF_COMBINED 262144u     // 64*2048 = 131072 floats
#define OFF_WC       393216u     // 2*2048 = 4096 floats
#define OFF_GX0      397312u     // [2][64][4096] = 524288 floats (K-half 0)
#define OFF_GX1      921600u     // [2][64][4096] = 524288 floats (K-half 1)
#define ZERO_BYTES   (262144u * 4u)   // Hbuf(tags) only

__device__ __forceinline__ float sigmoidf_(float x) {
  float t = __expf(-fabsf(x));
  float s = 1.0f / (1.0f + t);
  return x >= 0.f ? s : 1.f - s;
}
__device__ __forceinline__ float tanhf_(float x) {
  float t = __expf(-2.f * fabsf(x));
  float r = (1.f - t) / (1.f + t);
  return x >= 0.f ? r : -r;
}
__device__ __forceinline__ float dot4_(float4 a, float4 b) {
  return a.x * b.x + a.y * b.y + a.z * b.z + a.w * b.w;
}
__device__ __forceinline__ void fmax4_(float4& m, float4 v) {
  m.x = fmaxf(m.x, v.x); m.y = fmaxf(m.y, v.y);
  m.z = fmaxf(m.z, v.z); m.w = fmaxf(m.w, v.w);
}

// ============ K1: SEP find + segment max-pool -> combined[64][2048] ============
__global__ __launch_bounds__(256) void k_pool(const int* __restrict__ ids,
                                              const float* __restrict__ hs,
                                              float* __restrict__ ws) {
  int b = blockIdx.x >> 2;
  int quarter = blockIdx.x & 3;
  int tid = threadIdx.x;
  __shared__ int s0, s1, s2;
  if (tid == 0) { s0 = Lseq; s1 = Lseq; s2 = Lseq; }
  __syncthreads();
  int pA = tid, pB = tid + 256;
  int vA = ids[b * Lseq + pA], vB = ids[b * Lseq + pB];
  if (vA == SEP_ID) atomicMin(&s0, pA);
  if (vB == SEP_ID) atomicMin(&s0, pB);
  __syncthreads();
  if (vA == SEP_ID && pA > s0) atomicMin(&s1, pA);
  if (vB == SEP_ID && pB > s0) atomicMin(&s1, pB);
  __syncthreads();
  if (vA == SEP_ID && pA > s1) atomicMin(&s2, pA);
  if (vB == SEP_ID && pB > s1) atomicMin(&s2, pB);
  __syncthreads();
  int e1 = s1, e2 = s2;

  int gq = tid & 63, tp = tid >> 6;
  int c4 = quarter * 64 + gq;                 // float4 index within H (0..255)
  const float4* hp = (const float4*)(hs + (size_t)b * Lseq * Hd);
  float4 m1 = make_float4(-FLT_MAX, -FLT_MAX, -FLT_MAX, -FLT_MAX);
  float4 m2 = m1;
  for (int t = 1 + tp; t < e2; t += 32) {
#pragma unroll
    for (int u = 0; u < 8; ++u) {
      int tt = t + 4 * u;
      if (tt < e2) {
        float4 v = hp[(size_t)tt * 256 + c4];
        if (tt < e1) fmax4_(m1, v); else fmax4_(m2, v);
      }
    }
  }
  __shared__ float4 r1s[256];
  __shared__ float4 r2s[256];
  r1s[tid] = m1; r2s[tid] = m2;
  __syncthreads();
  if (tp == 0) {
    float4 a = r1s[tid], bb = r1s[tid + 64], c = r1s[tid + 128], d = r1s[tid + 192];
    float4 o1;
    o1.x = fmaxf(fmaxf(a.x, bb.x), fmaxf(c.x, d.x));
    o1.y = fmaxf(fmaxf(a.y, bb.y), fmaxf(c.y, d.y));
    o1.z = fmaxf(fmaxf(a.z, bb.z), fmaxf(c.z, d.z));
    o1.w = fmaxf(fmaxf(a.w, bb.w), fmaxf(c.w, d.w));
    a = r2s[tid]; bb = r2s[tid + 64]; c = r2s[tid + 128]; d = r2s[tid + 192];
    float4 o2;
    o2.x = fmaxf(fmaxf(a.x, bb.x), fmaxf(c.x, d.x));
    o2.y = fmaxf(fmaxf(a.y, bb.y), fmaxf(c.y, d.y));
    o2.z = fmaxf(fmaxf(a.z, bb.z), fmaxf(c.z, d.z));
    o2.w = fmaxf(fmaxf(a.w, bb.w), fmaxf(c.w, d.w));
    float4* cw = (float4*)(ws + OFF_COMBINED + (size_t)b * 2048);
    cw[c4] = o1;          // s1 pool -> channels [0,1024)
    cw[256 + c4] = o2;    // s2 pool -> channels [1024,2048)
  }
}

// ============ K2: xgemm [0,512) + wc blocks [512,544) ============
// (unchanged from R15.)
__global__ __launch_bounds__(256, 2) void k_xgemm(const float* __restrict__ wih_f,
                                                  const float* __restrict__ wih_b,
                                                  const float* __restrict__ w1,
                                                  const float* __restrict__ w2,
                                                  float* __restrict__ ws) {
  __shared__ float wl[2][64][36];
  __shared__ float cl[2][32][36];
  __shared__ float red[2][4][64];
  int d = blockIdx.x;
  int bid = 2 * ((d & 7) + 8 * ((d >> 3) >> 1)) + ((d >> 3) & 1);  // logical block
  int tid = threadIdx.x;

  if (bid >= 512) {              // ---- wc branch ----
    int lane = tid & 63;
    int jg = tid >> 6;                     // 0..3
    int km = (bid - 512) * 64 + lane;
    float a0 = 0.f, a1 = 0.f;
    int j0 = jg * 512;
#pragma unroll 8
    for (int j = j0; j < j0 + 512; ++j) {
      float v = w1[(size_t)j * 2048 + km];
      a0 += w2[j] * v;
      a1 += w2[2048 + j] * v;
    }
    red[0][jg][lane] = a0;
    red[1][jg][lane] = a1;
    __syncthreads();
    if (jg == 0) {
      float* wc = ws + OFF_WC;
      wc[km]        = red[0][0][lane] + red[0][1][lane] + red[0][2][lane] + red[0][3][lane];
      wc[2048 + km] = red[1][0][lane] + red[1][1][lane] + red[1][2][lane] + red[1][3][lane];
    }
    return;
  }

  int dir = bid >> 8;            // bid = dir(2) x jt(64) x tt(2) x kq(2)
  int rem = bid & 255;
  int jt  = rem >> 2;
  int tt  = (rem >> 1) & 1;
  int kq  = rem & 1;
  const float* wih = dir ? wih_b : wih_f;
  const float* comb = ws + OFF_COMBINED;
  float* gx = ws + (kq ? OFF_GX1 : OFF_GX0) + (size_t)dir * 64 * 4096;
  int jbase = jt * 64;
  int tbase = tt * 32;
  int jq = tid & 15, tq = tid >> 4;      // 16 x 16 thread grid
  int wrow0 = tid >> 3, wcol = tid & 7;
  int wrow1 = (tid + 256) >> 3;
  int crow = tid >> 3;

  float acc[4][2] = {};
  float4 wrg0, wrg1, crg;

  {
    int kab = kq * 1024;
    wrg0 = *(const float4*)&wih[(size_t)(jbase + wrow0) * 2048 + kab + wcol * 4];
    wrg1 = *(const float4*)&wih[(size_t)(jbase + wrow1) * 2048 + kab + wcol * 4];
    crg  = *(const float4*)&comb[(size_t)(tbase + crow) * 2048 + kab + wcol * 4];
    *(float4*)&wl[0][wrow0][wcol * 4] = wrg0;
    *(float4*)&wl[0][wrow1][wcol * 4] = wrg1;
    *(float4*)&cl[0][crow][wcol * 4]  = crg;
  }

  for (int kk = 0; kk < 32; ++kk) {
    int cur = kk & 1;
    if (kk < 31) {
      int kab = kq * 1024 + (kk + 1) * 32;
      wrg0 = *(const float4*)&wih[(size_t)(jbase + wrow0) * 2048 + kab + wcol * 4];
      wrg1 = *(const float4*)&wih[(size_t)(jbase + wrow1) * 2048 + kab + wcol * 4];
      crg  = *(const float4*)&comb[(size_t)(tbase + crow) * 2048 + kab + wcol * 4];
    }
    __syncthreads();
#pragma unroll
    for (int k4 = 0; k4 < 8; ++k4) {
      float4 wv[4], cv[2];
#pragma unroll
      for (int c = 0; c < 4; ++c) wv[c] = *(const float4*)&wl[cur][jq + 16 * c][k4 * 4];
#pragma unroll
      for (int u = 0; u < 2; ++u) cv[u] = *(const float4*)&cl[cur][tq + 16 * u][k4 * 4];
#pragma unroll
      for (int c = 0; c < 4; ++c)
#pragma unroll
        for (int u = 0; u < 2; ++u) acc[c][u] += dot4_(wv[c], cv[u]);
    }
    if (kk < 31) {
      int nxt = cur ^ 1;
      *(float4*)&wl[nxt][wrow0][wcol * 4] = wrg0;
      *(float4*)&wl[nxt][wrow1][wcol * 4] = wrg1;
      *(float4*)&cl[nxt][crow][wcol * 4]  = crg;
    }
  }
#pragma unroll
  for (int u = 0; u < 2; ++u)
#pragma unroll
    for (int c = 0; c < 4; ++c)
      gx[(size_t)(tbase + tq + 16 * u) * 4096 + jbase + jq + 16 * c] = acc[c][u];
}

// ============ K3: persistent AGPR-resident bidirectional LSTM ============
// R16: FAN-IN CUT. 64 blocks x 1024 threads (16 waves, 32 m/block, 2 m/wave —
// same per-wave code shape as R8/R14). The per-step all-to-all is a de-facto
// grid barrier whose cost scales with participant count; R9/R11/R14/R15 all
// plateaued at ~170us because they kept 256 blocks / 65536x4 poll-loads.
// Now: convoy max over 64 blocks (was 256), and each thread polls exactly ONE
// slot (1024 slots / 1024 threads) -> 4x less traffic at the L3 coherence
// point. Compute concentrates on 64 CUs (+0.3us/step) — cheap vs the convoy.
__global__ __launch_bounds__(1024, 1) void k_lstm(const float* __restrict__ whh_f,
                                                  const float* __restrict__ whh_b,
                                                  const float* __restrict__ bih_f,
                                                  const float* __restrict__ bhh_f,
                                                  const float* __restrict__ bih_b,
                                                  const float* __restrict__ bhh_b,
                                                  float* __restrict__ ws) {
  int wg = blockIdx.x;           // 0..63
  int dir = wg >> 5;
  int wgd = wg & 31;
  int tid = threadIdx.x;         // 0..1023
  int wave = tid >> 6, lane = tid & 63;
  int m0 = wgd * 32 + wave * 2;  // 32 m per block, 2 per wave
  const float* whh = dir ? whh_b : whh_f;
  const float* bih = dir ? bih_b : bih_f;
  const float* bhh = dir ? bhh_b : bhh_f;
  const float* gx0 = ws + OFF_GX0 + (size_t)dir * 64 * 4096;
  const float* gx1 = ws + OFF_GX1 + (size_t)dir * 64 * 4096;
  u64* hb = (u64*)(ws + OFF_HBUF);

  __shared__ float hsm[2][1024];

  float wr[4][2][16];
  float bias[4][2];
#pragma unroll
  for (int g = 0; g < 4; ++g)
#pragma unroll
    for (int mm = 0; mm < 2; ++mm) {
      const float* row = whh + (size_t)(g * 1024 + m0 + mm) * 1024;
#pragma unroll
      for (int j = 0; j < 16; ++j) wr[g][mm][j] = row[j * 64 + lane];
      bias[g][mm] = bih[g * 1024 + m0 + mm] + bhh[g * 1024 + m0 + mm];
    }
#pragma unroll
  for (int g = 0; g < 4; ++g)
#pragma unroll
    for (int mm = 0; mm < 2; ++mm)
#pragma unroll
      for (int j = 0; j < 16; ++j)
        asm volatile("" : "+v"(wr[g][mm][j]));

  float cst[2] = {0.f, 0.f};

  for (int t = 0; t < 64; ++t) {
    int ts = dir ? (63 - t) : t;
    const float* gxt0 = gx0 + (size_t)ts * 4096;
    const float* gxt1 = gx1 + (size_t)ts * 4096;
    float gxv0[4][2], gxv1[4][2];
#pragma unroll
    for (int g = 0; g < 4; ++g)
#pragma unroll
      for (int mm = 0; mm < 2; ++mm) {
        gxv0[g][mm] = gxt0[g * 1024 + m0 + mm];
        gxv1[g][mm] = gxt1[g * 1024 + m0 + mm];
      }

    float S[4][2];
    if (t > 0) {
      int sel = t & 1;
      const u64* hp = hb + ((size_t)(t - 1) * 2 + dir) * 1024;
      u64 etag = (u64)t;   // slot for step t-1 carries tag (t-1)+1 = t
      int guard = 0;
      for (;;) {           // each thread polls exactly ONE slot
        u64 x = __hip_atomic_load(hp + tid, __ATOMIC_RELAXED, __HIP_MEMORY_SCOPE_AGENT);
        if ((x >> 32) == etag) { hsm[sel][tid] = __uint_as_float((unsigned)x); break; }
        if (++guard > 2000000) break;           // safety escape (no hang)
        __builtin_amdgcn_s_sleep(1);
      }
      __syncthreads();                          // all 1024 h staged in hsm[sel]
      float acc[4][2] = {};
#pragma unroll
      for (int j = 0; j < 16; ++j) {
        float hv = hsm[sel][j * 64 + lane];
#pragma unroll
        for (int g = 0; g < 4; ++g) {
          acc[g][0] += wr[g][0][j] * hv;
          acc[g][1] += wr[g][1][j] * hv;
        }
      }
      // no second barrier: next step writes hsm[sel^1] (double-buffered)
      float a0 = acc[0][0], a1 = acc[0][1], a2 = acc[1][0], a3 = acc[1][1];
      float a4 = acc[2][0], a5 = acc[2][1], a6 = acc[3][0], a7 = acc[3][1];
      int l1 = lane & 1, l2 = lane & 2, l4 = lane & 4;
      float b0 = (l1 ? a1 : a0) + __shfl_xor(l1 ? a0 : a1, 1, 64);
      float b1 = (l1 ? a3 : a2) + __shfl_xor(l1 ? a2 : a3, 1, 64);
      float b2 = (l1 ? a5 : a4) + __shfl_xor(l1 ? a4 : a5, 1, 64);
      float b3 = (l1 ? a7 : a6) + __shfl_xor(l1 ? a6 : a7, 1, 64);
      float c0 = (l2 ? b1 : b0) + __shfl_xor(l2 ? b0 : b1, 2, 64);
      float c1 = (l2 ? b3 : b2) + __shfl_xor(l2 ? b2 : b3, 2, 64);
      float dd = (l4 ? c1 : c0) + __shfl_xor(l4 ? c0 : c1, 4, 64);
      dd += __shfl_xor(dd, 8, 64);
      dd += __shfl_xor(dd, 16, 64);
      dd += __shfl_xor(dd, 32, 64);
#pragma unroll
      for (int g = 0; g < 4; ++g) {
        S[g][0] = __shfl(dd, 2 * g + 0, 64);
        S[g][1] = __shfl(dd, 2 * g + 1, 64);
      }
    } else {
#pragma unroll
      for (int g = 0; g < 4; ++g) { S[g][0] = 0.f; S[g][1] = 0.f; }
    }

    float hnew[2];
#pragma unroll
    for (int mm = 0; mm < 2; ++mm) {
      float gi = S[0][mm] + gxv0[0][mm] + gxv1[0][mm] + bias[0][mm];
      float gf = S[1][mm] + gxv0[1][mm] + gxv1[1][mm] + bias[1][mm];
      float gg = S[2][mm] + gxv0[2][mm] + gxv1[2][mm] + bias[2][mm];
      float go = S[3][mm] + gxv0[3][mm] + gxv1[3][mm] + bias[3][mm];
      cst[mm] = sigmoidf_(gf) * cst[mm] + sigmoidf_(gi) * tanhf_(gg);
      hnew[mm] = sigmoidf_(go) * tanhf_(cst[mm]);
    }
    if (lane == 0) {
      u64* hw = hb + ((size_t)t * 2 + dir) * 1024 + m0;
      u64 p0 = ((u64)(t + 1) << 32) | (u64)__float_as_uint(hnew[0]);
      u64 p1 = ((u64)(t + 1) << 32) | (u64)__float_as_uint(hnew[1]);
      __hip_atomic_store(hw,     p0, __ATOMIC_RELAXED, __HIP_MEMORY_SCOPE_AGENT);
      __hip_atomic_store(hw + 1, p1, __ATOMIC_RELAXED, __HIP_MEMORY_SCOPE_AGENT);
    }
  }
}

// ============ K4b: logits[64][2] = lstm_out @ Wc^T + (b2 + w2@b1) ============
__global__ __launch_bounds__(256) void k_logits(const float* __restrict__ w2,
                                                const float* __restrict__ b1,
                                                const float* __restrict__ b2,
                                                const float* __restrict__ ws,
                                                float* __restrict__ out) {
  int ts = blockIdx.x;
  int tid = threadIdx.x;
  const float* wc = ws + OFF_WC;
  const u64* hb = (const u64*)(ws + OFF_HBUF);
  const u64* h0 = hb + ((size_t)ts * 2 + 0) * 1024;
  const u64* h1 = hb + ((size_t)(63 - ts) * 2 + 1) * 1024;
  float a0 = 0.f, a1 = 0.f;
#pragma unroll
  for (int e = 0; e < 8; ++e) {
    int k = tid + e * 256;
    u64 v = (k < 1024) ? h0[k] : h1[k - 1024];
    float hv = __uint_as_float((unsigned)v);
    a0 += hv * wc[k];
    a1 += hv * wc[2048 + k];
  }
#pragma unroll
  for (int e = 0; e < 8; ++e) {
    int j = tid + e * 256;
    float bv = b1[j];
    a0 += bv * w2[j];
    a1 += bv * w2[2048 + j];
  }
#pragma unroll
  for (int off = 32; off > 0; off >>= 1) {
    a0 += __shfl_xor(a0, off, 64);
    a1 += __shfl_xor(a1, off, 64);
  }
  __shared__ float red[2][4];
  int wave = tid >> 6, lane = tid & 63;
  if (lane == 0) { red[0][wave] = a0; red[1][wave] = a1; }
  __syncthreads();
  if (tid == 0) {
    out[ts * 2 + 0] = red[0][0] + red[0][1] + red[0][2] + red[0][3] + b2[0];
    out[ts * 2 + 1] = red[1][0] + red[1][1] + red[1][2] + red[1][3] + b2[1];
  }
}

extern "C" void kernel_launch(void* const* d_in, const int* in_sizes, int n_in,
                              void* d_out, int out_size, void* d_ws, size_t ws_size,
                              hipStream_t stream) {
  const int*   ids   = (const int*)d_in[0];
  const float* hs    = (const float*)d_in[1];
  const float* wih_f = (const float*)d_in[2];
  const float* whh_f = (const float*)d_in[3];
  const float* bih_f = (const float*)d_in[4];
  const float* bhh_f = (const float*)d_in[5];
  const float* wih_b = (const float*)d_in[6];
  const float* whh_b = (const float*)d_in[7];
  const float* bih_b = (const float*)d_in[8];
  const float* bhh_b = (const float*)d_in[9];
  const float* w1    = (const float*)d_in[10];
  const float* b1    = (const float*)d_in[11];
  const float* w2    = (const float*)d_in[12];
  const float* b2    = (const float*)d_in[13];
  float* ws = (float*)d_ws;
  float* out = (float*)d_out;

  // zero Hbuf tags only (graph-capturable; re-zeroed on every replay)
  hipMemsetAsync(ws + OFF_HBUF, 0, ZERO_BYTES, stream);

  k_pool  <<<dim3(256), dim3(256),  0, stream>>>(ids, hs, ws);
  k_xgemm <<<dim3(544), dim3(256),  0, stream>>>(wih_f, wih_b, w1, w2, ws);
  k_lstm  <<<dim3(64),  dim3(1024), 0, stream>>>(whh_f, whh_b, bih_f, bhh_f, bih_b, bhh_b, ws);
  k_logits<<<dim3(64),  dim3(256),  0, stream>>>(w2, b1, b2, ws, out);
}

// Round 17
// 332.728 us; speedup vs baseline: 2.2103x; 2.2103x over previous
//
#include <hip/hip_runtime.h>
#include <cfloat>
#include <cmath>

#define SEP_ID 102
#define Bsz 64
#define Lseq 512
#define Hd 1024

typedef unsigned long long u64;

// ---- workspace layout (float offsets) ----
// TOTAL = 1,445,888 floats = 5.78 MB — proven-safe footprint (R3/R6/R8-R15).
#define OFF_HBUF     0u          // u64[64][2][1024] = 262144 floats (8B aligned @0)
#define OFF_COMBINED 262144u     // 64*2048 = 131072 floats
#define OFF_WC       393216u     // 2*2048 = 4096 floats
#define OFF_GX0      397312u     // [2][64][4096] = 524288 floats (K-half 0)
#define OFF_GX1      921600u     // [2][64][4096] = 524288 floats (K-half 1)
#define ZERO_BYTES   (262144u * 4u)   // Hbuf(tags) only

__device__ __forceinline__ float sigmoidf_(float x) {
  float t = __expf(-fabsf(x));
  float s = 1.0f / (1.0f + t);
  return x >= 0.f ? s : 1.f - s;
}
__device__ __forceinline__ float tanhf_(float x) {
  float t = __expf(-2.f * fabsf(x));
  float r = (1.f - t) / (1.f + t);
  return x >= 0.f ? r : -r;
}
__device__ __forceinline__ float dot4_(float4 a, float4 b) {
  return a.x * b.x + a.y * b.y + a.z * b.z + a.w * b.w;
}
__device__ __forceinline__ void fmax4_(float4& m, float4 v) {
  m.x = fmaxf(m.x, v.x); m.y = fmaxf(m.y, v.y);
  m.z = fmaxf(m.z, v.z); m.w = fmaxf(m.w, v.w);
}

// ============ K1: SEP find + segment max-pool -> combined[64][2048] ============
__global__ __launch_bounds__(256) void k_pool(const int* __restrict__ ids,
                                              const float* __restrict__ hs,
                                              float* __restrict__ ws) {
  int b = blockIdx.x >> 2;
  int quarter = blockIdx.x & 3;
  int tid = threadIdx.x;
  __shared__ int s0, s1, s2;
  if (tid == 0) { s0 = Lseq; s1 = Lseq; s2 = Lseq; }
  __syncthreads();
  int pA = tid, pB = tid + 256;
  int vA = ids[b * Lseq + pA], vB = ids[b * Lseq + pB];
  if (vA == SEP_ID) atomicMin(&s0, pA);
  if (vB == SEP_ID) atomicMin(&s0, pB);
  __syncthreads();
  if (vA == SEP_ID && pA > s0) atomicMin(&s1, pA);
  if (vB == SEP_ID && pB > s0) atomicMin(&s1, pB);
  __syncthreads();
  if (vA == SEP_ID && pA > s1) atomicMin(&s2, pA);
  if (vB == SEP_ID && pB > s1) atomicMin(&s2, pB);
  __syncthreads();
  int e1 = s1, e2 = s2;

  int gq = tid & 63, tp = tid >> 6;
  int c4 = quarter * 64 + gq;                 // float4 index within H (0..255)
  const float4* hp = (const float4*)(hs + (size_t)b * Lseq * Hd);
  float4 m1 = make_float4(-FLT_MAX, -FLT_MAX, -FLT_MAX, -FLT_MAX);
  float4 m2 = m1;
  for (int t = 1 + tp; t < e2; t += 32) {
#pragma unroll
    for (int u = 0; u < 8; ++u) {
      int tt = t + 4 * u;
      if (tt < e2) {
        float4 v = hp[(size_t)tt * 256 + c4];
        if (tt < e1) fmax4_(m1, v); else fmax4_(m2, v);
      }
    }
  }
  __shared__ float4 r1s[256];
  __shared__ float4 r2s[256];
  r1s[tid] = m1; r2s[tid] = m2;
  __syncthreads();
  if (tp == 0) {
    float4 a = r1s[tid], bb = r1s[tid + 64], c = r1s[tid + 128], d = r1s[tid + 192];
    float4 o1;
    o1.x = fmaxf(fmaxf(a.x, bb.x), fmaxf(c.x, d.x));
    o1.y = fmaxf(fmaxf(a.y, bb.y), fmaxf(c.y, d.y));
    o1.z = fmaxf(fmaxf(a.z, bb.z), fmaxf(c.z, d.z));
    o1.w = fmaxf(fmaxf(a.w, bb.w), fmaxf(c.w, d.w));
    a = r2s[tid]; bb = r2s[tid + 64]; c = r2s[tid + 128]; d = r2s[tid + 192];
    float4 o2;
    o2.x = fmaxf(fmaxf(a.x, bb.x), fmaxf(c.x, d.x));
    o2.y = fmaxf(fmaxf(a.y, bb.y), fmaxf(c.y, d.y));
    o2.z = fmaxf(fmaxf(a.z, bb.z), fmaxf(c.z, d.z));
    o2.w = fmaxf(fmaxf(a.w, bb.w), fmaxf(c.w, d.w));
    float4* cw = (float4*)(ws + OFF_COMBINED + (size_t)b * 2048);
    cw[c4] = o1;          // s1 pool -> channels [0,1024)
    cw[256 + c4] = o2;    // s2 pool -> channels [1024,2048)
  }
}

// ============ K2: xgemm [0,512) + wc blocks [512,544) ============
// (unchanged from R15.)
__global__ __launch_bounds__(256, 2) void k_xgemm(const float* __restrict__ wih_f,
                                                  const float* __restrict__ wih_b,
                                                  const float* __restrict__ w1,
                                                  const float* __restrict__ w2,
                                                  float* __restrict__ ws) {
  __shared__ float wl[2][64][36];
  __shared__ float cl[2][32][36];
  __shared__ float red[2][4][64];
  int d = blockIdx.x;
  int bid = 2 * ((d & 7) + 8 * ((d >> 3) >> 1)) + ((d >> 3) & 1);  // logical block
  int tid = threadIdx.x;

  if (bid >= 512) {              // ---- wc branch ----
    int lane = tid & 63;
    int jg = tid >> 6;                     // 0..3
    int km = (bid - 512) * 64 + lane;
    float a0 = 0.f, a1 = 0.f;
    int j0 = jg * 512;
#pragma unroll 8
    for (int j = j0; j < j0 + 512; ++j) {
      float v = w1[(size_t)j * 2048 + km];
      a0 += w2[j] * v;
      a1 += w2[2048 + j] * v;
    }
    red[0][jg][lane] = a0;
    red[1][jg][lane] = a1;
    __syncthreads();
    if (jg == 0) {
      float* wc = ws + OFF_WC;
      wc[km]        = red[0][0][lane] + red[0][1][lane] + red[0][2][lane] + red[0][3][lane];
      wc[2048 + km] = red[1][0][lane] + red[1][1][lane] + red[1][2][lane] + red[1][3][lane];
    }
    return;
  }

  int dir = bid >> 8;            // bid = dir(2) x jt(64) x tt(2) x kq(2)
  int rem = bid & 255;
  int jt  = rem >> 2;
  int tt  = (rem >> 1) & 1;
  int kq  = rem & 1;
  const float* wih = dir ? wih_b : wih_f;
  const float* comb = ws + OFF_COMBINED;
  float* gx = ws + (kq ? OFF_GX1 : OFF_GX0) + (size_t)dir * 64 * 4096;
  int jbase = jt * 64;
  int tbase = tt * 32;
  int jq = tid & 15, tq = tid >> 4;      // 16 x 16 thread grid
  int wrow0 = tid >> 3, wcol = tid & 7;
  int wrow1 = (tid + 256) >> 3;
  int crow = tid >> 3;

  float acc[4][2] = {};
  float4 wrg0, wrg1, crg;

  {
    int kab = kq * 1024;
    wrg0 = *(const float4*)&wih[(size_t)(jbase + wrow0) * 2048 + kab + wcol * 4];
    wrg1 = *(const float4*)&wih[(size_t)(jbase + wrow1) * 2048 + kab + wcol * 4];
    crg  = *(const float4*)&comb[(size_t)(tbase + crow) * 2048 + kab + wcol * 4];
    *(float4*)&wl[0][wrow0][wcol * 4] = wrg0;
    *(float4*)&wl[0][wrow1][wcol * 4] = wrg1;
    *(float4*)&cl[0][crow][wcol * 4]  = crg;
  }

  for (int kk = 0; kk < 32; ++kk) {
    int cur = kk & 1;
    if (kk < 31) {
      int kab = kq * 1024 + (kk + 1) * 32;
      wrg0 = *(const float4*)&wih[(size_t)(jbase + wrow0) * 2048 + kab + wcol * 4];
      wrg1 = *(const float4*)&wih[(size_t)(jbase + wrow1) * 2048 + kab + wcol * 4];
      crg  = *(const float4*)&comb[(size_t)(tbase + crow) * 2048 + kab + wcol * 4];
    }
    __syncthreads();
#pragma unroll
    for (int k4 = 0; k4 < 8; ++k4) {
      float4 wv[4], cv[2];
#pragma unroll
      for (int c = 0; c < 4; ++c) wv[c] = *(const float4*)&wl[cur][jq + 16 * c][k4 * 4];
#pragma unroll
      for (int u = 0; u < 2; ++u) cv[u] = *(const float4*)&cl[cur][tq + 16 * u][k4 * 4];
#pragma unroll
      for (int c = 0; c < 4; ++c)
#pragma unroll
        for (int u = 0; u < 2; ++u) acc[c][u] += dot4_(wv[c], cv[u]);
    }
    if (kk < 31) {
      int nxt = cur ^ 1;
      *(float4*)&wl[nxt][wrow0][wcol * 4] = wrg0;
      *(float4*)&wl[nxt][wrow1][wcol * 4] = wrg1;
      *(float4*)&cl[nxt][crow][wcol * 4]  = crg;
    }
  }
#pragma unroll
  for (int u = 0; u < 2; ++u)
#pragma unroll
    for (int c = 0; c < 4; ++c)
      gx[(size_t)(tbase + tq + 16 * u) * 4096 + jbase + jq + 16 * c] = acc[c][u];
}

// ============ K3: persistent AGPR-resident bidirectional LSTM ============
// R17: CLEAN fan-in test. R16's 1024-thread block (4 waves/SIMD) cut the
// per-thread register budget to 128 -> the 128-float weight set SPILLED
// (VGPR=64, WRITE 24MB scratch signature) and confounded the experiment.
// Now: 128 blocks x 512 threads (8 waves/block, 1 block/CU = 2 waves/SIMD
// -> 256-reg budget, weights fit 2x over). Fan-in still halved vs R15
// (128 vs 256 blocks); each thread polls 2 slots, batched back-to-back.
__global__ __launch_bounds__(512, 1) void k_lstm(const float* __restrict__ whh_f,
                                                 const float* __restrict__ whh_b,
                                                 const float* __restrict__ bih_f,
                                                 const float* __restrict__ bhh_f,
                                                 const float* __restrict__ bih_b,
                                                 const float* __restrict__ bhh_b,
                                                 float* __restrict__ ws) {
  int wg = blockIdx.x;           // 0..127
  int dir = wg >> 6;
  int wgd = wg & 63;
  int tid = threadIdx.x;         // 0..511
  int wave = tid >> 6, lane = tid & 63;
  int m0 = wgd * 16 + wave * 2;  // 16 m per block, 2 per wave (8 waves)
  const float* whh = dir ? whh_b : whh_f;
  const float* bih = dir ? bih_b : bih_f;
  const float* bhh = dir ? bhh_b : bhh_f;
  const float* gx0 = ws + OFF_GX0 + (size_t)dir * 64 * 4096;
  const float* gx1 = ws + OFF_GX1 + (size_t)dir * 64 * 4096;
  u64* hb = (u64*)(ws + OFF_HBUF);

  __shared__ float hsm[2][1024];

  float wr[4][2][16];
  float bias[4][2];
#pragma unroll
  for (int g = 0; g < 4; ++g)
#pragma unroll
    for (int mm = 0; mm < 2; ++mm) {
      const float* row = whh + (size_t)(g * 1024 + m0 + mm) * 1024;
#pragma unroll
      for (int j = 0; j < 16; ++j) wr[g][mm][j] = row[j * 64 + lane];
      bias[g][mm] = bih[g * 1024 + m0 + mm] + bhh[g * 1024 + m0 + mm];
    }
#pragma unroll
  for (int g = 0; g < 4; ++g)
#pragma unroll
    for (int mm = 0; mm < 2; ++mm)
#pragma unroll
      for (int j = 0; j < 16; ++j)
        asm volatile("" : "+v"(wr[g][mm][j]));

  float cst[2] = {0.f, 0.f};

  for (int t = 0; t < 64; ++t) {
    int ts = dir ? (63 - t) : t;
    const float* gxt0 = gx0 + (size_t)ts * 4096;
    const float* gxt1 = gx1 + (size_t)ts * 4096;
    float gxv0[4][2], gxv1[4][2];
#pragma unroll
    for (int g = 0; g < 4; ++g)
#pragma unroll
      for (int mm = 0; mm < 2; ++mm) {
        gxv0[g][mm] = gxt0[g * 1024 + m0 + mm];
        gxv1[g][mm] = gxt1[g * 1024 + m0 + mm];
      }

    float S[4][2];
    if (t > 0) {
      int sel = t & 1;
      const u64* hp = hb + ((size_t)(t - 1) * 2 + dir) * 1024;
      u64 etag = (u64)t;   // slot for step t-1 carries tag (t-1)+1 = t
      unsigned pend = 3u;
      int guard = 0;
      for (;;) {           // 2 slots per thread, loads batched back-to-back
        u64 x0 = __hip_atomic_load(hp + tid,       __ATOMIC_RELAXED, __HIP_MEMORY_SCOPE_AGENT);
        u64 x1 = __hip_atomic_load(hp + tid + 512, __ATOMIC_RELAXED, __HIP_MEMORY_SCOPE_AGENT);
        if ((pend & 1u) && ((x0 >> 32) == etag)) { hsm[sel][tid]       = __uint_as_float((unsigned)x0); pend &= ~1u; }
        if ((pend & 2u) && ((x1 >> 32) == etag)) { hsm[sel][tid + 512] = __uint_as_float((unsigned)x1); pend &= ~2u; }
        if (!pend) break;
        if (++guard > 2000000) break;           // safety escape (no hang)
        __builtin_amdgcn_s_sleep(1);
      }
      __syncthreads();                          // all 1024 h staged in hsm[sel]
      float acc[4][2] = {};
#pragma unroll
      for (int j = 0; j < 16; ++j) {
        float hv = hsm[sel][j * 64 + lane];
#pragma unroll
        for (int g = 0; g < 4; ++g) {
          acc[g][0] += wr[g][0][j] * hv;
          acc[g][1] += wr[g][1][j] * hv;
        }
      }
      // no second barrier: next step writes hsm[sel^1] (double-buffered)
      float a0 = acc[0][0], a1 = acc[0][1], a2 = acc[1][0], a3 = acc[1][1];
      float a4 = acc[2][0], a5 = acc[2][1], a6 = acc[3][0], a7 = acc[3][1];
      int l1 = lane & 1, l2 = lane & 2, l4 = lane & 4;
      float b0 = (l1 ? a1 : a0) + __shfl_xor(l1 ? a0 : a1, 1, 64);
      float b1 = (l1 ? a3 : a2) + __shfl_xor(l1 ? a2 : a3, 1, 64);
      float b2 = (l1 ? a5 : a4) + __shfl_xor(l1 ? a4 : a5, 1, 64);
      float b3 = (l1 ? a7 : a6) + __shfl_xor(l1 ? a6 : a7, 1, 64);
      float c0 = (l2 ? b1 : b0) + __shfl_xor(l2 ? b0 : b1, 2, 64);
      float c1 = (l2 ? b3 : b2) + __shfl_xor(l2 ? b2 : b3, 2, 64);
      float dd = (l4 ? c1 : c0) + __shfl_xor(l4 ? c0 : c1, 4, 64);
      dd += __shfl_xor(dd, 8, 64);
      dd += __shfl_xor(dd, 16, 64);
      dd += __shfl_xor(dd, 32, 64);
#pragma unroll
      for (int g = 0; g < 4; ++g) {
        S[g][0] = __shfl(dd, 2 * g + 0, 64);
        S[g][1] = __shfl(dd, 2 * g + 1, 64);
      }
    } else {
#pragma unroll
      for (int g = 0; g < 4; ++g) { S[g][0] = 0.f; S[g][1] = 0.f; }
    }

    float hnew[2];
#pragma unroll
    for (int mm = 0; mm < 2; ++mm) {
      float gi = S[0][mm] + gxv0[0][mm] + gxv1[0][mm] + bias[0][mm];
      float gf = S[1][mm] + gxv0[1][mm] + gxv1[1][mm] + bias[1][mm];
      float gg = S[2][mm] + gxv0[2][mm] + gxv1[2][mm] + bias[2][mm];
      float go = S[3][mm] + gxv0[3][mm] + gxv1[3][mm] + bias[3][mm];
      cst[mm] = sigmoidf_(gf) * cst[mm] + sigmoidf_(gi) * tanhf_(gg);
      hnew[mm] = sigmoidf_(go) * tanhf_(cst[mm]);
    }
    if (lane == 0) {
      u64* hw = hb + ((size_t)t * 2 + dir) * 1024 + m0;
      u64 p0 = ((u64)(t + 1) << 32) | (u64)__float_as_uint(hnew[0]);
      u64 p1 = ((u64)(t + 1) << 32) | (u64)__float_as_uint(hnew[1]);
      __hip_atomic_store(hw,     p0, __ATOMIC_RELAXED, __HIP_MEMORY_SCOPE_AGENT);
      __hip_atomic_store(hw + 1, p1, __ATOMIC_RELAXED, __HIP_MEMORY_SCOPE_AGENT);
    }
  }
}

// ============ K4b: logits[64][2] = lstm_out @ Wc^T + (b2 + w2@b1) ============
__global__ __launch_bounds__(256) void k_logits(const float* __restrict__ w2,
                                                const float* __restrict__ b1,
                                                const float* __restrict__ b2,
                                                const float* __restrict__ ws,
                                                float* __restrict__ out) {
  int ts = blockIdx.x;
  int tid = threadIdx.x;
  const float* wc = ws + OFF_WC;
  const u64* hb = (const u64*)(ws + OFF_HBUF);
  const u64* h0 = hb + ((size_t)ts * 2 + 0) * 1024;
  const u64* h1 = hb + ((size_t)(63 - ts) * 2 + 1) * 1024;
  float a0 = 0.f, a1 = 0.f;
#pragma unroll
  for (int e = 0; e < 8; ++e) {
    int k = tid + e * 256;
    u64 v = (k < 1024) ? h0[k] : h1[k - 1024];
    float hv = __uint_as_float((unsigned)v);
    a0 += hv * wc[k];
    a1 += hv * wc[2048 + k];
  }
#pragma unroll
  for (int e = 0; e < 8; ++e) {
    int j = tid + e * 256;
    float bv = b1[j];
    a0 += bv * w2[j];
    a1 += bv * w2[2048 + j];
  }
#pragma unroll
  for (int off = 32; off > 0; off >>= 1) {
    a0 += __shfl_xor(a0, off, 64);
    a1 += __shfl_xor(a1, off, 64);
  }
  __shared__ float red[2][4];
  int wave = tid >> 6, lane = tid & 63;
  if (lane == 0) { red[0][wave] = a0; red[1][wave] = a1; }
  __syncthreads();
  if (tid == 0) {
    out[ts * 2 + 0] = red[0][0] + red[0][1] + red[0][2] + red[0][3] + b2[0];
    out[ts * 2 + 1] = red[1][0] + red[1][1] + red[1][2] + red[1][3] + b2[1];
  }
}

extern "C" void kernel_launch(void* const* d_in, const int* in_sizes, int n_in,
                              void* d_out, int out_size, void* d_ws, size_t ws_size,
                              hipStream_t stream) {
  const int*   ids   = (const int*)d_in[0];
  const float* hs    = (const float*)d_in[1];
  const float* wih_f = (const float*)d_in[2];
  const float* whh_f = (const float*)d_in[3];
  const float* bih_f = (const float*)d_in[4];
  const float* bhh_f = (const float*)d_in[5];
  const float* wih_b = (const float*)d_in[6];
  const float* whh_b = (const float*)d_in[7];
  const float* bih_b = (const float*)d_in[8];
  const float* bhh_b = (const float*)d_in[9];
  const float* w1    = (const float*)d_in[10];
  const float* b1    = (const float*)d_in[11];
  const float* w2    = (const float*)d_in[12];
  const float* b2    = (const float*)d_in[13];
  float* ws = (float*)d_ws;
  float* out = (float*)d_out;

  // zero Hbuf tags only (graph-capturable; re-zeroed on every replay)
  hipMemsetAsync(ws + OFF_HBUF, 0, ZERO_BYTES, stream);

  k_pool  <<<dim3(256), dim3(256), 0, stream>>>(ids, hs, ws);
  k_xgemm <<<dim3(544), dim3(256), 0, stream>>>(wih_f, wih_b, w1, w2, ws);
  k_lstm  <<<dim3(128), dim3(512), 0, stream>>>(whh_f, whh_b, bih_f, bhh_f, bih_b, bhh_b, ws);
  k_logits<<<dim3(64),  dim3(256), 0, stream>>>(w2, b1, b2, ws, out);
}

// Round 18
// 259.418 us; speedup vs baseline: 2.8349x; 1.2826x over previous
//
#include <hip/hip_runtime.h>
#include <cfloat>
#include <cmath>

#define SEP_ID 102
#define Bsz 64
#define Lseq 512
#define Hd 1024

typedef unsigned long long u64;

// ---- workspace layout (float offsets) ----
// TOTAL = 1,445,888 floats = 5.78 MB — proven-safe footprint (R3/R6/R8-R15).
#define OFF_HBUF     0u          // u64[64][2][1024] = 262144 floats (8B aligned @0)
#define OFF_COMBINED 262144u     // 64*2048 = 131072 floats
#define OFF_WC       393216u     // 2*2048 = 4096 floats
#define OFF_GX0      397312u     // [2][64][4096] = 524288 floats (K-half 0)
#define OFF_GX1      921600u     // [2][64][4096] = 524288 floats (K-half 1)

__device__ __forceinline__ float sigmoidf_(float x) {
  float t = __expf(-fabsf(x));
  float s = 1.0f / (1.0f + t);
  return x >= 0.f ? s : 1.f - s;
}
__device__ __forceinline__ float tanhf_(float x) {
  float t = __expf(-2.f * fabsf(x));
  float r = (1.f - t) / (1.f + t);
  return x >= 0.f ? r : -r;
}
__device__ __forceinline__ float dot4_(float4 a, float4 b) {
  return a.x * b.x + a.y * b.y + a.z * b.z + a.w * b.w;
}
__device__ __forceinline__ void fmax4_(float4& m, float4 v) {
  m.x = fmaxf(m.x, v.x); m.y = fmaxf(m.y, v.y);
  m.z = fmaxf(m.z, v.z); m.w = fmaxf(m.w, v.w);
}

// ============ K1: SEP find + segment max-pool -> combined[64][2048] ============
// R18: also zeroes the hbuf tag region (2 u64/thread, disjoint from pooling) —
// replaces the separate hipMemsetAsync dispatch. Kernel-boundary ordering
// (pool -> xgemm -> lstm, one stream) makes the zeros visible before any poll.
__global__ __launch_bounds__(256) void k_pool(const int* __restrict__ ids,
                                              const float* __restrict__ hs,
                                              float* __restrict__ ws) {
  int b = blockIdx.x >> 2;
  int quarter = blockIdx.x & 3;
  int tid = threadIdx.x;

  // zero hbuf tags: 131072 u64 / (256 blk x 256 thr) = 2 u64 per thread
  {
    u64* hb = (u64*)(ws + OFF_HBUF);
    int base = (blockIdx.x * 256 + tid) * 2;
    hb[base] = 0ull;
    hb[base + 1] = 0ull;
  }

  __shared__ int s0, s1, s2;
  if (tid == 0) { s0 = Lseq; s1 = Lseq; s2 = Lseq; }
  __syncthreads();
  int pA = tid, pB = tid + 256;
  int vA = ids[b * Lseq + pA], vB = ids[b * Lseq + pB];
  if (vA == SEP_ID) atomicMin(&s0, pA);
  if (vB == SEP_ID) atomicMin(&s0, pB);
  __syncthreads();
  if (vA == SEP_ID && pA > s0) atomicMin(&s1, pA);
  if (vB == SEP_ID && pB > s0) atomicMin(&s1, pB);
  __syncthreads();
  if (vA == SEP_ID && pA > s1) atomicMin(&s2, pA);
  if (vB == SEP_ID && pB > s1) atomicMin(&s2, pB);
  __syncthreads();
  int e1 = s1, e2 = s2;

  int gq = tid & 63, tp = tid >> 6;
  int c4 = quarter * 64 + gq;                 // float4 index within H (0..255)
  const float4* hp = (const float4*)(hs + (size_t)b * Lseq * Hd);
  float4 m1 = make_float4(-FLT_MAX, -FLT_MAX, -FLT_MAX, -FLT_MAX);
  float4 m2 = m1;
  for (int t = 1 + tp; t < e2; t += 16) {
#pragma unroll
    for (int u = 0; u < 4; ++u) {
      int tt = t + 4 * u;
      if (tt < e2) {
        float4 v = hp[(size_t)tt * 256 + c4];
        if (tt < e1) fmax4_(m1, v); else fmax4_(m2, v);
      }
    }
  }
  __shared__ float4 r1s[256];
  __shared__ float4 r2s[256];
  r1s[tid] = m1; r2s[tid] = m2;
  __syncthreads();
  if (tp == 0) {
    float4 a = r1s[tid], bb = r1s[tid + 64], c = r1s[tid + 128], d = r1s[tid + 192];
    float4 o1;
    o1.x = fmaxf(fmaxf(a.x, bb.x), fmaxf(c.x, d.x));
    o1.y = fmaxf(fmaxf(a.y, bb.y), fmaxf(c.y, d.y));
    o1.z = fmaxf(fmaxf(a.z, bb.z), fmaxf(c.z, d.z));
    o1.w = fmaxf(fmaxf(a.w, bb.w), fmaxf(c.w, d.w));
    a = r2s[tid]; bb = r2s[tid + 64]; c = r2s[tid + 128]; d = r2s[tid + 192];
    float4 o2;
    o2.x = fmaxf(fmaxf(a.x, bb.x), fmaxf(c.x, d.x));
    o2.y = fmaxf(fmaxf(a.y, bb.y), fmaxf(c.y, d.y));
    o2.z = fmaxf(fmaxf(a.z, bb.z), fmaxf(c.z, d.z));
    o2.w = fmaxf(fmaxf(a.w, bb.w), fmaxf(c.w, d.w));
    float4* cw = (float4*)(ws + OFF_COMBINED + (size_t)b * 2048);
    cw[c4] = o1;          // s1 pool -> channels [0,1024)
    cw[256 + c4] = o2;    // s2 pool -> channels [1024,2048)
  }
}

// ============ K2: xgemm [0,512) + wc blocks [512,544) ============
// (R13/R14 version — best measured; no XCD swizzle, plain blockIdx.)
__global__ __launch_bounds__(256, 2) void k_xgemm(const float* __restrict__ wih_f,
                                                  const float* __restrict__ wih_b,
                                                  const float* __restrict__ w1,
                                                  const float* __restrict__ w2,
                                                  float* __restrict__ ws) {
  __shared__ float wl[2][64][36];
  __shared__ float cl[2][32][36];
  __shared__ float red[2][4][64];
  int bid = blockIdx.x;
  int tid = threadIdx.x;

  if (bid >= 512) {              // ---- wc branch ----
    int lane = tid & 63;
    int jg = tid >> 6;                     // 0..3
    int km = (bid - 512) * 64 + lane;
    float a0 = 0.f, a1 = 0.f;
    int j0 = jg * 512;
#pragma unroll 8
    for (int j = j0; j < j0 + 512; ++j) {
      float v = w1[(size_t)j * 2048 + km];
      a0 += w2[j] * v;
      a1 += w2[2048 + j] * v;
    }
    red[0][jg][lane] = a0;
    red[1][jg][lane] = a1;
    __syncthreads();
    if (jg == 0) {
      float* wc = ws + OFF_WC;
      wc[km]        = red[0][0][lane] + red[0][1][lane] + red[0][2][lane] + red[0][3][lane];
      wc[2048 + km] = red[1][0][lane] + red[1][1][lane] + red[1][2][lane] + red[1][3][lane];
    }
    return;
  }

  int dir = bid >> 8;            // bid = dir(2) x jt(64) x tt(2) x kq(2)
  int rem = bid & 255;
  int jt  = rem >> 2;
  int tt  = (rem >> 1) & 1;
  int kq  = rem & 1;
  const float* wih = dir ? wih_b : wih_f;
  const float* comb = ws + OFF_COMBINED;
  float* gx = ws + (kq ? OFF_GX1 : OFF_GX0) + (size_t)dir * 64 * 4096;
  int jbase = jt * 64;
  int tbase = tt * 32;
  int jq = tid & 15, tq = tid >> 4;      // 16 x 16 thread grid
  int wrow0 = tid >> 3, wcol = tid & 7;
  int wrow1 = (tid + 256) >> 3;
  int crow = tid >> 3;

  float acc[4][2] = {};
  float4 wrg0, wrg1, crg;

  {
    int kab = kq * 1024;
    wrg0 = *(const float4*)&wih[(size_t)(jbase + wrow0) * 2048 + kab + wcol * 4];
    wrg1 = *(const float4*)&wih[(size_t)(jbase + wrow1) * 2048 + kab + wcol * 4];
    crg  = *(const float4*)&comb[(size_t)(tbase + crow) * 2048 + kab + wcol * 4];
    *(float4*)&wl[0][wrow0][wcol * 4] = wrg0;
    *(float4*)&wl[0][wrow1][wcol * 4] = wrg1;
    *(float4*)&cl[0][crow][wcol * 4]  = crg;
  }

  for (int kk = 0; kk < 32; ++kk) {
    int cur = kk & 1;
    if (kk < 31) {
      int kab = kq * 1024 + (kk + 1) * 32;
      wrg0 = *(const float4*)&wih[(size_t)(jbase + wrow0) * 2048 + kab + wcol * 4];
      wrg1 = *(const float4*)&wih[(size_t)(jbase + wrow1) * 2048 + kab + wcol * 4];
      crg  = *(const float4*)&comb[(size_t)(tbase + crow) * 2048 + kab + wcol * 4];
    }
    __syncthreads();
#pragma unroll
    for (int k4 = 0; k4 < 8; ++k4) {
      float4 wv[4], cv[2];
#pragma unroll
      for (int c = 0; c < 4; ++c) wv[c] = *(const float4*)&wl[cur][jq + 16 * c][k4 * 4];
#pragma unroll
      for (int u = 0; u < 2; ++u) cv[u] = *(const float4*)&cl[cur][tq + 16 * u][k4 * 4];
#pragma unroll
      for (int c = 0; c < 4; ++c)
#pragma unroll
        for (int u = 0; u < 2; ++u) acc[c][u] += dot4_(wv[c], cv[u]);
    }
    if (kk < 31) {
      int nxt = cur ^ 1;
      *(float4*)&wl[nxt][wrow0][wcol * 4] = wrg0;
      *(float4*)&wl[nxt][wrow1][wcol * 4] = wrg1;
      *(float4*)&cl[nxt][crow][wcol * 4]  = crg;
    }
  }
#pragma unroll
  for (int u = 0; u < 2; ++u)
#pragma unroll
    for (int c = 0; c < 4; ++c)
      gx[(size_t)(tbase + tq + 16 * u) * 4096 + jbase + jq + 16 * c] = acc[c][u];
}

// ============ K3: persistent AGPR-resident bidirectional LSTM ============
// R18 = exact R14 revert (best measured: 168us). 256 blocks x 256 thr,
// 2 m/wave; 4-slot batched poll (all loads issued back-to-back, ~1 RTT/round);
// LDS stage + 1 barrier + FMA + 1 barrier; 18-shfl packed reduce.
// Fan-in experiments (R16 64-blk: spilled; R17 128-blk x 512thr: 237us) both
// lost to this shape — the ~2.6us/step exchange is its measured optimum.
__global__ __launch_bounds__(256, 2) void k_lstm(const float* __restrict__ whh_f,
                                                 const float* __restrict__ whh_b,
                                                 const float* __restrict__ bih_f,
                                                 const float* __restrict__ bhh_f,
                                                 const float* __restrict__ bih_b,
                                                 const float* __restrict__ bhh_b,
                                                 float* __restrict__ ws) {
  int wg = blockIdx.x;
  int dir = wg >> 7;
  int wgd = wg & 127;
  int tid = threadIdx.x;
  int wave = tid >> 6, lane = tid & 63;
  int m0 = wgd * 8 + wave * 2;
  const float* whh = dir ? whh_b : whh_f;
  const float* bih = dir ? bih_b : bih_f;
  const float* bhh = dir ? bhh_b : bhh_f;
  const float* gx0 = ws + OFF_GX0 + (size_t)dir * 64 * 4096;
  const float* gx1 = ws + OFF_GX1 + (size_t)dir * 64 * 4096;
  u64* hb = (u64*)(ws + OFF_HBUF);

  __shared__ float hsm[1024];

  float wr[4][2][16];
  float bias[4][2];
#pragma unroll
  for (int g = 0; g < 4; ++g)
#pragma unroll
    for (int mm = 0; mm < 2; ++mm) {
      const float* row = whh + (size_t)(g * 1024 + m0 + mm) * 1024;
#pragma unroll
      for (int j = 0; j < 16; ++j) wr[g][mm][j] = row[j * 64 + lane];
      bias[g][mm] = bih[g * 1024 + m0 + mm] + bhh[g * 1024 + m0 + mm];
    }
#pragma unroll
  for (int g = 0; g < 4; ++g)
#pragma unroll
    for (int mm = 0; mm < 2; ++mm)
#pragma unroll
      for (int j = 0; j < 16; ++j)
        asm volatile("" : "+v"(wr[g][mm][j]));

  float cst[2] = {0.f, 0.f};

  for (int t = 0; t < 64; ++t) {
    int ts = dir ? (63 - t) : t;
    const float* gxt0 = gx0 + (size_t)ts * 4096;
    const float* gxt1 = gx1 + (size_t)ts * 4096;
    float gxv0[4][2], gxv1[4][2];
#pragma unroll
    for (int g = 0; g < 4; ++g)
#pragma unroll
      for (int mm = 0; mm < 2; ++mm) {
        gxv0[g][mm] = gxt0[g * 1024 + m0 + mm];
        gxv1[g][mm] = gxt1[g * 1024 + m0 + mm];
      }

    float S[4][2];
    if (t > 0) {
      const u64* hp = hb + ((size_t)(t - 1) * 2 + dir) * 1024;
      u64 etag = (u64)t;   // slot for step t-1 carries tag (t-1)+1 = t
      unsigned pend = 0xFu;
      int guard = 0;
      for (;;) {
        // all 4 independent loads issued back-to-back: one RTT per round
        u64 x0 = __hip_atomic_load(hp + tid,       __ATOMIC_RELAXED, __HIP_MEMORY_SCOPE_AGENT);
        u64 x1 = __hip_atomic_load(hp + tid + 256, __ATOMIC_RELAXED, __HIP_MEMORY_SCOPE_AGENT);
        u64 x2 = __hip_atomic_load(hp + tid + 512, __ATOMIC_RELAXED, __HIP_MEMORY_SCOPE_AGENT);
        u64 x3 = __hip_atomic_load(hp + tid + 768, __ATOMIC_RELAXED, __HIP_MEMORY_SCOPE_AGENT);
        if ((pend & 1u) && ((x0 >> 32) == etag)) { hsm[tid]       = __uint_as_float((unsigned)x0); pend &= ~1u; }
        if ((pend & 2u) && ((x1 >> 32) == etag)) { hsm[tid + 256] = __uint_as_float((unsigned)x1); pend &= ~2u; }
        if ((pend & 4u) && ((x2 >> 32) == etag)) { hsm[tid + 512] = __uint_as_float((unsigned)x2); pend &= ~4u; }
        if ((pend & 8u) && ((x3 >> 32) == etag)) { hsm[tid + 768] = __uint_as_float((unsigned)x3); pend &= ~8u; }
        if (!pend) break;
        if (++guard > 1000000) break;           // safety escape (no hang)
        __builtin_amdgcn_s_sleep(1);
      }
      __syncthreads();                          // all 1024 h staged in LDS
      float acc[4][2] = {};
#pragma unroll
      for (int j = 0; j < 16; ++j) {
        float hv = hsm[j * 64 + lane];
#pragma unroll
        for (int g = 0; g < 4; ++g) {
          acc[g][0] += wr[g][0][j] * hv;
          acc[g][1] += wr[g][1][j] * hv;
        }
      }
      __syncthreads();                          // hsm reads done; next step may overwrite
      float a0 = acc[0][0], a1 = acc[0][1], a2 = acc[1][0], a3 = acc[1][1];
      float a4 = acc[2][0], a5 = acc[2][1], a6 = acc[3][0], a7 = acc[3][1];
      int l1 = lane & 1, l2 = lane & 2, l4 = lane & 4;
      float b0 = (l1 ? a1 : a0) + __shfl_xor(l1 ? a0 : a1, 1, 64);
      float b1 = (l1 ? a3 : a2) + __shfl_xor(l1 ? a2 : a3, 1, 64);
      float b2 = (l1 ? a5 : a4) + __shfl_xor(l1 ? a4 : a5, 1, 64);
      float b3 = (l1 ? a7 : a6) + __shfl_xor(l1 ? a6 : a7, 1, 64);
      float c0 = (l2 ? b1 : b0) + __shfl_xor(l2 ? b0 : b1, 2, 64);
      float c1 = (l2 ? b3 : b2) + __shfl_xor(l2 ? b2 : b3, 2, 64);
      float dd = (l4 ? c1 : c0) + __shfl_xor(l4 ? c0 : c1, 4, 64);
      dd += __shfl_xor(dd, 8, 64);
      dd += __shfl_xor(dd, 16, 64);
      dd += __shfl_xor(dd, 32, 64);
#pragma unroll
      for (int g = 0; g < 4; ++g) {
        S[g][0] = __shfl(dd, 2 * g + 0, 64);
        S[g][1] = __shfl(dd, 2 * g + 1, 64);
      }
    } else {
#pragma unroll
      for (int g = 0; g < 4; ++g) { S[g][0] = 0.f; S[g][1] = 0.f; }
    }

    float hnew[2];
#pragma unroll
    for (int mm = 0; mm < 2; ++mm) {
      float gi = S[0][mm] + gxv0[0][mm] + gxv1[0][mm] + bias[0][mm];
      float gf = S[1][mm] + gxv0[1][mm] + gxv1[1][mm] + bias[1][mm];
      float gg = S[2][mm] + gxv0[2][mm] + gxv1[2][mm] + bias[2][mm];
      float go = S[3][mm] + gxv0[3][mm] + gxv1[3][mm] + bias[3][mm];
      cst[mm] = sigmoidf_(gf) * cst[mm] + sigmoidf_(gi) * tanhf_(gg);
      hnew[mm] = sigmoidf_(go) * tanhf_(cst[mm]);
    }
    if (lane == 0) {
      u64* hw = hb + ((size_t)t * 2 + dir) * 1024 + m0;
      u64 p0 = ((u64)(t + 1) << 32) | (u64)__float_as_uint(hnew[0]);
      u64 p1 = ((u64)(t + 1) << 32) | (u64)__float_as_uint(hnew[1]);
      __hip_atomic_store(hw,     p0, __ATOMIC_RELAXED, __HIP_MEMORY_SCOPE_AGENT);
      __hip_atomic_store(hw + 1, p1, __ATOMIC_RELAXED, __HIP_MEMORY_SCOPE_AGENT);
    }
  }
}

// ============ K4b: logits[64][2] = lstm_out @ Wc^T + (b2 + w2@b1) ============
__global__ __launch_bounds__(256) void k_logits(const float* __restrict__ w2,
                                                const float* __restrict__ b1,
                                                const float* __restrict__ b2,
                                                const float* __restrict__ ws,
                                                float* __restrict__ out) {
  int ts = blockIdx.x;
  int tid = threadIdx.x;
  const float* wc = ws + OFF_WC;
  const u64* hb = (const u64*)(ws + OFF_HBUF);
  const u64* h0 = hb + ((size_t)ts * 2 + 0) * 1024;
  const u64* h1 = hb + ((size_t)(63 - ts) * 2 + 1) * 1024;
  float a0 = 0.f, a1 = 0.f;
#pragma unroll
  for (int e = 0; e < 8; ++e) {
    int k = tid + e * 256;
    u64 v = (k < 1024) ? h0[k] : h1[k - 1024];
    float hv = __uint_as_float((unsigned)v);
    a0 += hv * wc[k];
    a1 += hv * wc[2048 + k];
  }
#pragma unroll
  for (int e = 0; e < 8; ++e) {
    int j = tid + e * 256;
    float bv = b1[j];
    a0 += bv * w2[j];
    a1 += bv * w2[2048 + j];
  }
#pragma unroll
  for (int off = 32; off > 0; off >>= 1) {
    a0 += __shfl_xor(a0, off, 64);
    a1 += __shfl_xor(a1, off, 64);
  }
  __shared__ float red[2][4];
  int wave = tid >> 6, lane = tid & 63;
  if (lane == 0) { red[0][wave] = a0; red[1][wave] = a1; }
  __syncthreads();
  if (tid == 0) {
    out[ts * 2 + 0] = red[0][0] + red[0][1] + red[0][2] + red[0][3] + b2[0];
    out[ts * 2 + 1] = red[1][0] + red[1][1] + red[1][2] + red[1][3] + b2[1];
  }
}

extern "C" void kernel_launch(void* const* d_in, const int* in_sizes, int n_in,
                              void* d_out, int out_size, void* d_ws, size_t ws_size,
                              hipStream_t stream) {
  const int*   ids   = (const int*)d_in[0];
  const float* hs    = (const float*)d_in[1];
  const float* wih_f = (const float*)d_in[2];
  const float* whh_f = (const float*)d_in[3];
  const float* bih_f = (const float*)d_in[4];
  const float* bhh_f = (const float*)d_in[5];
  const float* wih_b = (const float*)d_in[6];
  const float* whh_b = (const float*)d_in[7];
  const float* bih_b = (const float*)d_in[8];
  const float* bhh_b = (const float*)d_in[9];
  const float* w1    = (const float*)d_in[10];
  const float* b1    = (const float*)d_in[11];
  const float* w2    = (const float*)d_in[12];
  const float* b2    = (const float*)d_in[13];
  float* ws = (float*)d_ws;
  float* out = (float*)d_out;

  // hbuf tag zeroing folded into k_pool (saves a dispatch; re-zeroed each call)
  k_pool  <<<dim3(256), dim3(256), 0, stream>>>(ids, hs, ws);
  k_xgemm <<<dim3(544), dim3(256), 0, stream>>>(wih_f, wih_b, w1, w2, ws);
  k_lstm  <<<dim3(256), dim3(256), 0, stream>>>(whh_f, whh_b, bih_f, bhh_f, bih_b, bhh_b, ws);
  k_logits<<<dim3(64),  dim3(256), 0, stream>>>(w2, b1, b2, ws, out);
}